// Round 5
// baseline (337.815 us; speedup 1.0000x reference)
//
#include <hip/hip_runtime.h>
#include <math.h>

#define BATCH 8
#define HW_N 409600          // 640*640
#define HW4 (HW_N / 4)       // 102400
#define NBLK 200             // pixel-kernel blocks per batch (512 float4/block)

// k1s per-batch reduction slots
#define NP 48
#define J_AK   0             // kernel dice: sum pk*gk*km
#define J_BK   1             //              sum pk*pk*km
#define J_CK   2             //              sum gk*km
#define J_AT   3             // text dice:   sum pt over pos&tm
#define J_BTP  4             //              sum pt^2 over pos&tm
#define J_BTN  5             //              sum pt^2 over neg&tm (all-neg-selected)
#define J_CPOS 6             // count(pos & tm)
#define J_CNEG 7             // count(!pos)
#define J_CNTK 8             // +(s-1), s=1..8
#define J_SUMK 16            // +(s-1)*4+c  (32)

__device__ __forceinline__ unsigned f2key(float x) {
    unsigned u = __float_as_uint(x);
    return (u & 0x80000000u) ? ~u : (u | 0x80000000u);
}
__device__ __forceinline__ float key2f(unsigned k) {
    unsigned u = (k & 0x80000000u) ? (k & 0x7fffffffu) : ~k;
    return __uint_as_float(u);
}
__device__ __forceinline__ float wred64(float v) {
#pragma unroll
    for (int o = 32; o > 0; o >>= 1) v += __shfl_xor(v, o, 64);
    return v;
}
__device__ __forceinline__ float wredmin64(float v) {
#pragma unroll
    for (int o = 32; o > 0; o >>= 1) v = fminf(v, __shfl_xor(v, o, 64));
    return v;
}
__device__ __forceinline__ float f4c(const float4& v, int p) {
    return p == 0 ? v.x : p == 1 ? v.y : p == 2 ? v.z : v.w;
}
__device__ __forceinline__ int i4c(const int4& v, int p) {
    return p == 0 ? v.x : p == 1 ? v.y : p == 2 ? v.z : v.w;
}

// ---------------------------------------------------------------------------
// K1: heavy pass. Per iteration, ALL 10 vector loads are needed at pixel 0 so
// the compiler must issue them as a batch (MLP). Per-block sums -> 48 global
// atomics; the last block per batch (ticket) reduces + OHEM-decides + means.
// ---------------------------------------------------------------------------
__global__ __launch_bounds__(256)
void k1_main(const float4* __restrict__ Tl, const float4* __restrict__ Kl,
             const float4* __restrict__ Fv, const float4* __restrict__ Tm,
             const int4* __restrict__ Ltk, const int4* __restrict__ Lkk,
             float* __restrict__ k1s, unsigned* __restrict__ pk8,
             unsigned* __restrict__ minkeyinv, unsigned* __restrict__ cnt1,
             float* __restrict__ thr, unsigned* __restrict__ kval,
             unsigned* __restrict__ fb, float* __restrict__ kms) {
    const int b = blockIdx.y;
    const int tid = threadIdx.x;
    const int wid = tid >> 6, lane = tid & 63;
    const long base4 = (long)b * HW4;
    const long f04 = (long)b * 4 * HW4;

    __shared__ float sK[32];
    __shared__ unsigned cKs[8];
    __shared__ float wacc[4][6];
    __shared__ float wmin[4];
    __shared__ unsigned cPW[4], cNW[4];
    __shared__ unsigned lastS;
    __shared__ float ss[NP];

    if (tid < 32) sK[tid] = 0.f;
    else if (tid < 40) cKs[tid - 32] = 0u;
    __syncthreads();

    float r0 = 0.f, r1 = 0.f, r2 = 0.f, r3 = 0.f, r4 = 0.f, r5 = 0.f;
    float vmin = INFINITY;
    unsigned cpos = 0, cneg = 0;

#pragma unroll
    for (int it = 0; it < 2; ++it) {
        const int i4 = blockIdx.x * 512 + it * 256 + tid;
        const float4 tl4 = Tl[base4 + i4];
        const float4 kl4 = Kl[base4 + i4];
        const float4 tm4 = Tm[base4 + i4];
        const int4 lt4 = Ltk[base4 + i4];
        const int4 lk4 = Lkk[base4 + i4];
        const float4 F0v = Fv[f04 + i4];
        const float4 F1v = Fv[f04 + HW4 + i4];
        const float4 F2v = Fv[f04 + 2 * HW4 + i4];
        const float4 F3v = Fv[f04 + 3 * HW4 + i4];
        unsigned pkw = 0u;
#pragma unroll
        for (int p = 0; p < 4; ++p) {
            float tl = f4c(tl4, p), kl = f4c(kl4, p), m = f4c(tm4, p);
            int ltk = i4c(lt4, p), lkk = i4c(lk4, p);
            bool tmb = m > 0.5f;
            bool selt = tl > 0.f;      // sigmoid(x)>0.5 <=> x>0
            bool selk = kl > 0.f;
            bool pos = ltk > 0;        // gt_text == (gt_text_key > 0)
            float gkf = (lkk > 0) ? 1.f : 0.f;
            float km = (selt && tmb) ? 1.f : 0.f;
            float pkv = 1.f / (1.f + __expf(-kl));
            float ptv = 1.f / (1.f + __expf(-tl));
            r0 = fmaf(pkv * gkf, km, r0);
            r1 = fmaf(pkv * pkv, km, r1);
            r2 = fmaf(gkf, km, r2);
            float ptm = (pos && tmb) ? 1.f : 0.f;
            float ntm = (!pos && tmb) ? 1.f : 0.f;
            r3 = fmaf(ptv, ptm, r3);
            r4 = fmaf(ptv * ptv, ptm, r4);
            r5 = fmaf(ptv * ptv, ntm, r5);
            cpos += __popcll(__ballot(pos && tmb));
            cneg += __popcll(__ballot(!pos));
            vmin = fminf(vmin, pos ? INFINITY : tl);
            int lk = (selk && tmb) ? lkk : 0;
            if (lk > 0) {
                atomicAdd(&sK[(lk - 1) * 4 + 0], f4c(F0v, p));
                atomicAdd(&sK[(lk - 1) * 4 + 1], f4c(F1v, p));
                atomicAdd(&sK[(lk - 1) * 4 + 2], f4c(F2v, p));
                atomicAdd(&sK[(lk - 1) * 4 + 3], f4c(F3v, p));
                atomicAdd(&cKs[lk - 1], 1u);
            }
            pkw |= ((tmb ? 1u : 0u) | (selt ? 2u : 0u) | ((unsigned)ltk << 2)) << (8 * p);
        }
        pk8[base4 + i4] = pkw;
    }

    r0 = wred64(r0); r1 = wred64(r1); r2 = wred64(r2);
    r3 = wred64(r3); r4 = wred64(r4); r5 = wred64(r5);
    vmin = wredmin64(vmin);
    if (lane == 0) {
        wacc[wid][0] = r0; wacc[wid][1] = r1; wacc[wid][2] = r2;
        wacc[wid][3] = r3; wacc[wid][4] = r4; wacc[wid][5] = r5;
        wmin[wid] = vmin; cPW[wid] = cpos; cNW[wid] = cneg;
    }
    __syncthreads();
    float v = 0.f;
    if (tid < 6) v = wacc[0][tid] + wacc[1][tid] + wacc[2][tid] + wacc[3][tid];
    else if (tid == 6) v = (float)(cPW[0] + cPW[1] + cPW[2] + cPW[3]);
    else if (tid == 7) v = (float)(cNW[0] + cNW[1] + cNW[2] + cNW[3]);
    else if (tid < 16) v = (float)cKs[tid - 8];
    else if (tid < 48) v = sK[tid - 16];
    if (tid < 48) atomicAdd(&k1s[b * NP + tid], v);
    if (tid == 48) {
        float mn = fminf(fminf(wmin[0], wmin[1]), fminf(wmin[2], wmin[3]));
        if (mn < INFINITY) atomicMax(&minkeyinv[b], ~f2key(mn));
    }
    __threadfence();
    __syncthreads();
    if (tid == 0) lastS = (atomicAdd(&cnt1[b], 1u) == NBLK - 1u) ? 1u : 0u;
    __syncthreads();
    if (!lastS) return;

    // ---- fused per-batch reduce + OHEM decision + kernel means ----
    __threadfence();
    if (tid < NP) ss[tid] = atomicAdd(&k1s[b * NP + tid], 0.f);   // coherent read
    __syncthreads();
    if (tid == 0) {
        unsigned pos = (unsigned)(ss[J_CPOS] + 0.5f);
        unsigned neg = (unsigned)(ss[J_CNEG] + 0.5f);
        unsigned k = min(3u * pos, neg);
        kval[b] = k;
        if (pos == 0u || k == 0u) { thr[b] = -INFINITY; fb[b] = 1u; }
        else if (k == neg) {
            unsigned cur = atomicMax(&minkeyinv[b], 0u);          // coherent read
            thr[b] = key2f(~cur); fb[b] = 1u;
        } else fb[b] = 0u;                                        // rare: radix path
    }
    if (tid >= 64 && tid < 96) {
        int t = tid - 64, s = t >> 2;
        kms[b * 32 + t] = ss[J_SUMK + t] / fmaxf(ss[J_CNTK + s], 1.f);
    }
}

// ---------------------------------------------------------------------------
// K_RARE: exact k-th-largest negative logit via 4-pass radix select.
// Early-exits in the common (fb=1) case.
// ---------------------------------------------------------------------------
__global__ __launch_bounds__(256)
void k_rare(const float* __restrict__ Tl, const unsigned char* __restrict__ pk8b,
            const unsigned* __restrict__ fb, const unsigned* __restrict__ kval,
            float* __restrict__ thr) {
    const int b = blockIdx.x;
    if (fb[b]) return;
    __shared__ unsigned hist[256];
    __shared__ unsigned sj, spre;
    const long base = (long)b * HW_N;
    if (threadIdx.x == 0) { sj = kval[b]; spre = 0u; }
    __syncthreads();
    for (int pass = 0; pass < 4; ++pass) {
        const int shift = 24 - 8 * pass;
        hist[threadIdx.x] = 0u;
        __syncthreads();
        const unsigned pref = spre;
        for (int i = threadIdx.x; i < HW_N; i += 256) {
            if ((pk8b[base + i] >> 2) != 0u) continue;   // pos pixel
            unsigned key = f2key(Tl[base + i]);
            if (pass == 0 || (key >> (shift + 8)) == pref)
                atomicAdd(&hist[(key >> shift) & 0xFFu], 1u);
        }
        __syncthreads();
        if (threadIdx.x == 0) {
            unsigned j = sj, cum = 0;
            for (int d = 255; d >= 0; --d) {
                cum += hist[d];
                if (cum >= j) {
                    sj = j - (cum - hist[d]);
                    spre = (pref << 8) | (unsigned)d;
                    break;
                }
            }
        }
        __syncthreads();
    }
    if (threadIdx.x == 0) thr[b] = key2f(spre);
}

// ---------------------------------------------------------------------------
// K_NEGFIX: rare path only — SUBTRACT pt^2 of excluded negatives (tl < thr).
// ---------------------------------------------------------------------------
__global__ __launch_bounds__(256)
void k_negfix(const float4* __restrict__ Tl, const unsigned* __restrict__ pk8,
              const unsigned* __restrict__ fb, const float* __restrict__ thr,
              float* __restrict__ k1s) {
    const int b = blockIdx.y;
    if (fb[b]) return;
    const int tid = threadIdx.x;
    const long base4 = (long)b * HW4;
    const float tb = thr[b];
    float acc = 0.f;
#pragma unroll
    for (int it = 0; it < 2; ++it) {
        const int i4 = blockIdx.x * 512 + it * 256 + tid;
        const float4 tl4 = Tl[base4 + i4];
        const unsigned pkw = pk8[base4 + i4];
#pragma unroll
        for (int p = 0; p < 4; ++p) {
            unsigned byte = (pkw >> (8 * p)) & 0xFFu;
            bool tmb = byte & 1u;
            bool neg = (byte >> 2) == 0u;
            float tl = f4c(tl4, p);
            if (neg && tmb && tl < tb) {
                float pt = 1.f / (1.f + __expf(-tl));
                acc = fmaf(pt, pt, acc);
            }
        }
    }
    acc = wred64(acc);
    __shared__ float wa[4];
    if ((tid & 63) == 0) wa[tid >> 6] = acc;
    __syncthreads();
    if (tid == 0) {
        float s = wa[0] + wa[1] + wa[2] + wa[3];
        if (s != 0.f) atomicAdd(&k1s[b * NP + J_BTN], -s);
    }
}

// ---------------------------------------------------------------------------
// K5: aggregation pass — reads Fv + packed plane; register accumulators for
// sum_l and cnt_t; last block (global ticket) computes the final scalar.
// ---------------------------------------------------------------------------
__global__ __launch_bounds__(256)
void k5_agg(const unsigned* __restrict__ pk8, const float4* __restrict__ Fv,
            const float* __restrict__ kms, const float* __restrict__ k1s,
            float* __restrict__ slg, unsigned* __restrict__ tick,
            float* __restrict__ out) {
    const int b = blockIdx.y;
    const int tid = threadIdx.x, wid = tid >> 6, lane = tid & 63;
    __shared__ float Kml[32];
    __shared__ float wacc[4][16];
    __shared__ unsigned lastS;
    __shared__ float laS[8], ldS[8];
    __shared__ float KmS[256];
    if (tid < 32) Kml[tid] = kms[b * 32 + tid];
    __syncthreads();
    const long base4 = (long)b * HW4;
    const long f04 = (long)b * 4 * HW4;

    float sl8[8] = {0.f, 0.f, 0.f, 0.f, 0.f, 0.f, 0.f, 0.f};
    float ct8[8] = {0.f, 0.f, 0.f, 0.f, 0.f, 0.f, 0.f, 0.f};

#pragma unroll
    for (int it = 0; it < 2; ++it) {
        const int i4 = blockIdx.x * 512 + it * 256 + tid;
        const unsigned pkw = pk8[base4 + i4];
        const float4 F0v = Fv[f04 + i4];
        const float4 F1v = Fv[f04 + HW4 + i4];
        const float4 F2v = Fv[f04 + 2 * HW4 + i4];
        const float4 F3v = Fv[f04 + 3 * HW4 + i4];
#pragma unroll
        for (int p = 0; p < 4; ++p) {
            unsigned byte = (pkw >> (8 * p)) & 0xFFu;
            int lt = ((byte & 3u) == 3u) ? (int)(byte >> 2) : 0;
            int kb = (lt > 0 ? lt - 1 : 0) * 4;
            float d0 = f4c(F0v, p) - Kml[kb + 0];
            float d1 = f4c(F1v, p) - Kml[kb + 1];
            float d2 = f4c(F2v, p) - Kml[kb + 2];
            float d3 = f4c(F3v, p) - Kml[kb + 3];
            float d = sqrtf(fmaf(d0, d0, fmaf(d1, d1, fmaf(d2, d2, d3 * d3))));
            float t = fmaxf(d - 0.5f, 0.f);
            float pl = __logf(fmaf(t, t, 1.f));
#pragma unroll
            for (int s = 1; s <= 8; ++s) {
                float e = (lt == s) ? 1.f : 0.f;
                sl8[s - 1] = fmaf(e, pl, sl8[s - 1]);
                ct8[s - 1] += e;
            }
        }
    }

#pragma unroll
    for (int j = 0; j < 8; ++j) { sl8[j] = wred64(sl8[j]); ct8[j] = wred64(ct8[j]); }
    if (lane == 0) {
#pragma unroll
        for (int j = 0; j < 8; ++j) { wacc[wid][j] = sl8[j]; wacc[wid][8 + j] = ct8[j]; }
    }
    __syncthreads();
    if (tid < 16) {
        float v = wacc[0][tid] + wacc[1][tid] + wacc[2][tid] + wacc[3][tid];
        atomicAdd(&slg[b * 16 + tid], v);
    }
    __threadfence();
    __syncthreads();
    if (tid == 0) lastS = (atomicAdd(tick, 1u) == (unsigned)(NBLK * BATCH - 1)) ? 1u : 0u;
    __syncthreads();
    if (!lastS) return;

    // ---- fused final combine ----
    __threadfence();
    KmS[tid] = kms[tid];
    __syncthreads();
#pragma unroll
    for (int half = 0; half < 2; ++half) {
        int bb = wid * 2 + half;
        const float* s1 = k1s + bb * NP;
        float aggs = 0.f, aggc = 0.f;
        if (lane >= 1 && lane <= 8) {
            float ctv = atomicAdd(&slg[bb * 16 + 8 + lane - 1], 0.f);
            float ckv = s1[J_CNTK + lane - 1];
            if (ctv > 0.f && ckv > 0.f) {
                aggs = atomicAdd(&slg[bb * 16 + lane - 1], 0.f) / fmaxf(ctv, 1.f);
                aggc = 1.f;
            }
        }
        float diss = 0.f, disc = 0.f;
        {
            int i = 1 + (lane >> 3), j = 1 + (lane & 7);
            if (i != j && s1[J_CNTK + i - 1] > 0.f && s1[J_CNTK + j - 1] > 0.f) {
                float d2 = 0.f;
#pragma unroll
                for (int c = 0; c < 4; ++c) {
                    float df = KmS[bb * 32 + (i - 1) * 4 + c] -
                               KmS[bb * 32 + (j - 1) * 4 + c];
                    d2 = fmaf(df, df, d2);
                }
                float kd = sqrtf(d2);
                float t = fmaxf(3.f - kd, 0.f);
                diss = __logf(fmaf(t, t, 1.f));
                disc = 1.f;
            }
        }
        aggs = wred64(aggs); aggc = wred64(aggc);
        diss = wred64(diss); disc = wred64(disc);
        if (lane == 0) {
            laS[bb] = aggs / fmaxf(aggc, 1.f);
            ldS[bb] = diss / fmaxf(disc, 1.f);
        }
    }
    __syncthreads();
    if (tid == 0) {
        float Lt = 0.f, Lk = 0.f, La = 0.f, Ld = 0.f;
        for (int bb = 0; bb < BATCH; ++bb) {
            const float* a = k1s + bb * NP;
            Lk += 1.f - 2.f * a[J_AK] / ((a[J_BK] + 1e-6f) + (a[J_CK] + 1e-6f));
            float btv = a[J_BTP] + a[J_BTN];
            Lt += 1.f - 2.f * a[J_AT] / ((btv + 1e-6f) + (a[J_CPOS] + 1e-6f));
            La += laS[bb]; Ld += ldS[bb];
        }
        out[0] = Lt / BATCH + 0.5f * (Lk / BATCH) + 0.25f * (La / BATCH + Ld / BATCH);
    }
}

// ---------------------------------------------------------------------------
extern "C" void kernel_launch(void* const* d_in, const int* in_sizes, int n_in,
                              void* d_out, int out_size, void* d_ws, size_t ws_size,
                              hipStream_t stream) {
    (void)in_sizes; (void)n_in; (void)out_size; (void)ws_size;
    const float4* Tl = (const float4*)d_in[0];   // pre_text_logits
    const float4* Kl = (const float4*)d_in[1];   // pre_kernel_logits
    const float4* Fv = (const float4*)d_in[2];   // similarity_vector [B,C,H,W]
    const float4* Tm = (const float4*)d_in[5];   // train_mask
    const int4* Ltk = (const int4*)d_in[6];      // gt_text_key
    const int4* Lkk = (const int4*)d_in[7];      // gt_kernel_key
    float* out = (float*)d_out;

    // ws layout (u32 units). memset region first: k1s, slg, minkeyinv, cnt1, tick.
    float* k1s = (float*)d_ws;                         // 8*48 = 384
    float* slg = k1s + BATCH * NP;                     // 8*16 = 128
    unsigned* minkeyinv = (unsigned*)(slg + BATCH * 16); // 8
    unsigned* cnt1 = minkeyinv + BATCH;                // 8
    unsigned* tick = cnt1 + BATCH;                     // 4 (1 used)
    float* thr = (float*)(tick + 4);                   // 8
    unsigned* kval = (unsigned*)(thr + BATCH);         // 8
    unsigned* fb = kval + BATCH;                       // 8
    float* kms = (float*)(fb + BATCH);                 // 8*32 = 256
    unsigned* pk8 = (unsigned*)(kms + BATCH * 32);     // 8*HW4

    hipMemsetAsync(d_ws, 0,
                   (size_t)(BATCH * NP + BATCH * 16 + BATCH + BATCH + 4) * 4,
                   stream);

    dim3 g(NBLK, BATCH);
    k1_main<<<g, 256, 0, stream>>>(Tl, Kl, Fv, Tm, Ltk, Lkk, k1s, pk8,
                                   minkeyinv, cnt1, thr, kval, fb, kms);
    k_rare<<<BATCH, 256, 0, stream>>>((const float*)d_in[0],
                                      (const unsigned char*)pk8, fb, kval, thr);
    k_negfix<<<g, 256, 0, stream>>>(Tl, pk8, fb, thr, k1s);
    k5_agg<<<g, 256, 0, stream>>>(pk8, Fv, kms, k1s, slg, tick, out);
}

// Round 6
// 78.246 us; speedup vs baseline: 4.3174x; 4.3174x over previous
//
#include <hip/hip_runtime.h>
#include <math.h>

#define BATCH 8
#define HW_N 409600          // 640*640
#define HW4 (HW_N / 4)       // 102400
#define NBLK 200             // pixel-kernel blocks per batch (512 float4/block)

// k1s per-batch reduction slots
#define NP 48
#define J_AK   0             // kernel dice: sum pk*gk*km
#define J_BK   1             //              sum pk*pk*km
#define J_CK   2             //              sum gk*km
#define J_AT   3             // text dice:   sum pt over pos&tm
#define J_BTP  4             //              sum pt^2 over pos&tm
#define J_BTN  5             //              sum pt^2 over ALL neg&tm (negfix subtracts)
#define J_CPOS 6             // count(pos & tm)
#define J_CNEG 7             // count(!pos)
#define J_CNTK 8             // +(s-1), s=1..8
#define J_SUMK 16            // +(s-1)*4+c  (32)

__device__ __forceinline__ unsigned f2key(float x) {
    unsigned u = __float_as_uint(x);
    return (u & 0x80000000u) ? ~u : (u | 0x80000000u);
}
__device__ __forceinline__ float key2f(unsigned k) {
    unsigned u = (k & 0x80000000u) ? (k & 0x7fffffffu) : ~k;
    return __uint_as_float(u);
}
__device__ __forceinline__ float wred64(float v) {
#pragma unroll
    for (int o = 32; o > 0; o >>= 1) v += __shfl_xor(v, o, 64);
    return v;
}
__device__ __forceinline__ float wredmin64(float v) {
#pragma unroll
    for (int o = 32; o > 0; o >>= 1) v = fminf(v, __shfl_xor(v, o, 64));
    return v;
}
__device__ __forceinline__ float f4c(const float4& v, int p) {
    return p == 0 ? v.x : p == 1 ? v.y : p == 2 ? v.z : v.w;
}
__device__ __forceinline__ int i4c(const int4& v, int p) {
    return p == 0 ? v.x : p == 1 ? v.y : p == 2 ? v.z : v.w;
}

// ---------------------------------------------------------------------------
// K1: heavy pass. Both iterations' 20 vector loads are issued up front and
// pinned by a single asm so the compiler cannot sink them (MLP). Per-block
// partials -> part[] (contention-free); tiny k1_reduce kernel finishes.
// ---------------------------------------------------------------------------
__global__ __launch_bounds__(256)
void k1_main(const float4* __restrict__ Tl, const float4* __restrict__ Kl,
             const float4* __restrict__ Fv, const float4* __restrict__ Tm,
             const int4* __restrict__ Ltk, const int4* __restrict__ Lkk,
             float* __restrict__ part, unsigned* __restrict__ pk8,
             unsigned* __restrict__ minkeyinv) {
    const int b = blockIdx.y;
    const int tid = threadIdx.x;
    const int wid = tid >> 6, lane = tid & 63;
    const long base4 = (long)b * HW4;
    const long f04 = (long)b * 4 * HW4;

    __shared__ float sK[32];
    __shared__ unsigned cKs[8];
    __shared__ float wacc[4][8];
    __shared__ float wmin[4];
    if (tid < 32) sK[tid] = 0.f;
    else if (tid < 40) cKs[tid - 32] = 0u;
    __syncthreads();

    const int i0 = blockIdx.x * 512 + tid;
    const int i1 = i0 + 256;

    // ---- issue ALL 20 loads, then pin (forces batched issue, one wait) ----
    const float4 tlA = Tl[base4 + i0],  tlB = Tl[base4 + i1];
    const float4 klA = Kl[base4 + i0],  klB = Kl[base4 + i1];
    const float4 tmA = Tm[base4 + i0],  tmB = Tm[base4 + i1];
    const int4   ltA = Ltk[base4 + i0], ltB = Ltk[base4 + i1];
    const int4   lkA = Lkk[base4 + i0], lkB = Lkk[base4 + i1];
    const float4 f0A = Fv[f04 + i0],            f0B = Fv[f04 + i1];
    const float4 f1A = Fv[f04 + HW4 + i0],      f1B = Fv[f04 + HW4 + i1];
    const float4 f2A = Fv[f04 + 2 * HW4 + i0],  f2B = Fv[f04 + 2 * HW4 + i1];
    const float4 f3A = Fv[f04 + 3 * HW4 + i0],  f3B = Fv[f04 + 3 * HW4 + i1];
    asm volatile("" ::
        "v"(tlA.x), "v"(tlB.x), "v"(klA.x), "v"(klB.x), "v"(tmA.x), "v"(tmB.x),
        "v"(f0A.x), "v"(f0B.x), "v"(f1A.x), "v"(f1B.x),
        "v"(f2A.x), "v"(f2B.x), "v"(f3A.x), "v"(f3B.x),
        "v"(ltA.x), "v"(ltB.x), "v"(lkA.x), "v"(lkB.x));

    float r0 = 0.f, r1 = 0.f, r2 = 0.f, r3 = 0.f, r4 = 0.f, r5 = 0.f;
    float cpos = 0.f, cneg = 0.f;
    float vmin = INFINITY;

#pragma unroll
    for (int it = 0; it < 2; ++it) {
        const float4 tl4 = it ? tlB : tlA;
        const float4 kl4 = it ? klB : klA;
        const float4 tm4 = it ? tmB : tmA;
        const int4   lt4 = it ? ltB : ltA;
        const int4   lk4 = it ? lkB : lkA;
        const float4 F0v = it ? f0B : f0A;
        const float4 F1v = it ? f1B : f1A;
        const float4 F2v = it ? f2B : f2A;
        const float4 F3v = it ? f3B : f3A;
        unsigned pkw = 0u;
#pragma unroll
        for (int p = 0; p < 4; ++p) {
            float tl = f4c(tl4, p), kl = f4c(kl4, p), m = f4c(tm4, p);
            int ltk = i4c(lt4, p), lkk = i4c(lk4, p);
            bool tmb = m > 0.5f;
            bool selt = tl > 0.f;      // sigmoid(x)>0.5 <=> x>0
            bool selk = kl > 0.f;
            bool pos = ltk > 0;        // gt_text == (gt_text_key > 0)
            float gkf = (lkk > 0) ? 1.f : 0.f;
            float km = (selt && tmb) ? 1.f : 0.f;
            float pkv = 1.f / (1.f + __expf(-kl));
            float ptv = 1.f / (1.f + __expf(-tl));
            r0 = fmaf(pkv * gkf, km, r0);
            r1 = fmaf(pkv * pkv, km, r1);
            r2 = fmaf(gkf, km, r2);
            float ptm = (pos && tmb) ? 1.f : 0.f;
            float ntm = (!pos && tmb) ? 1.f : 0.f;
            r3 = fmaf(ptv, ptm, r3);
            r4 = fmaf(ptv * ptv, ptm, r4);
            r5 = fmaf(ptv * ptv, ntm, r5);
            cpos += ptm;
            cneg += pos ? 0.f : 1.f;
            vmin = fminf(vmin, pos ? INFINITY : tl);
            int lk = (selk && tmb) ? lkk : 0;
            if (lk > 0) {
                atomicAdd(&sK[(lk - 1) * 4 + 0], f4c(F0v, p));
                atomicAdd(&sK[(lk - 1) * 4 + 1], f4c(F1v, p));
                atomicAdd(&sK[(lk - 1) * 4 + 2], f4c(F2v, p));
                atomicAdd(&sK[(lk - 1) * 4 + 3], f4c(F3v, p));
                atomicAdd(&cKs[lk - 1], 1u);
            }
            pkw |= ((tmb ? 1u : 0u) | (selt ? 2u : 0u) | ((unsigned)ltk << 2)) << (8 * p);
        }
        pk8[base4 + (it ? i1 : i0)] = pkw;
    }

    r0 = wred64(r0); r1 = wred64(r1); r2 = wred64(r2);
    r3 = wred64(r3); r4 = wred64(r4); r5 = wred64(r5);
    cpos = wred64(cpos); cneg = wred64(cneg);
    vmin = wredmin64(vmin);
    if (lane == 0) {
        wacc[wid][0] = r0; wacc[wid][1] = r1; wacc[wid][2] = r2;
        wacc[wid][3] = r3; wacc[wid][4] = r4; wacc[wid][5] = r5;
        wacc[wid][6] = cpos; wacc[wid][7] = cneg;
        wmin[wid] = vmin;
    }
    __syncthreads();
    if (tid < NP) {
        float v;
        if (tid < 8)       v = wacc[0][tid] + wacc[1][tid] + wacc[2][tid] + wacc[3][tid];
        else if (tid < 16) v = (float)cKs[tid - 8];
        else               v = sK[tid - 16];
        part[((size_t)b * NP + tid) * NBLK + blockIdx.x] = v;
    }
    if (tid == 48) {
        float mn = fminf(fminf(wmin[0], wmin[1]), fminf(wmin[2], wmin[3]));
        if (mn < INFINITY) atomicMax(&minkeyinv[b], ~f2key(mn));
    }
}

// ---------------------------------------------------------------------------
// K1R: reduce per-block partials, OHEM decision, kernel means.
// ---------------------------------------------------------------------------
__global__ __launch_bounds__(256)
void k1_reduce(const float* __restrict__ part, const unsigned* __restrict__ minkeyinv,
               float* __restrict__ k1s, float* __restrict__ kms,
               float* __restrict__ thr, unsigned* __restrict__ kval,
               unsigned* __restrict__ fb) {
    const int b = blockIdx.x;
    const int tid = threadIdx.x, wid = tid >> 6, lane = tid & 63;
    __shared__ float ss[NP];
    for (int j = wid; j < NP; j += 4) {
        const float* p = part + ((size_t)b * NP + j) * NBLK;
        float v = 0.f;
        for (int i = lane; i < NBLK; i += 64) v += p[i];
        v = wred64(v);
        if (lane == 0) ss[j] = v;
    }
    __syncthreads();
    if (tid == 0) {
        unsigned pos = (unsigned)(ss[J_CPOS] + 0.5f);
        unsigned neg = (unsigned)(ss[J_CNEG] + 0.5f);
        unsigned k = min(3u * pos, neg);
        kval[b] = k;
        if (pos == 0u || k == 0u) { thr[b] = -INFINITY; fb[b] = 1u; }
        else if (k == neg)        { thr[b] = key2f(~minkeyinv[b]); fb[b] = 1u; }
        else                      { fb[b] = 0u; }   // rare: radix path
    }
    if (tid < NP) k1s[b * NP + tid] = ss[tid];
    if (tid >= 64 && tid < 96) {
        int t = tid - 64, s = t >> 2;
        kms[b * 32 + t] = ss[J_SUMK + t] / fmaxf(ss[J_CNTK + s], 1.f);
    }
}

// ---------------------------------------------------------------------------
// K_RARE: exact k-th-largest negative logit via 4-pass radix select.
// Early-exits in the common (fb=1) case.
// ---------------------------------------------------------------------------
__global__ __launch_bounds__(256)
void k_rare(const float* __restrict__ Tl, const unsigned char* __restrict__ pk8b,
            const unsigned* __restrict__ fb, const unsigned* __restrict__ kval,
            float* __restrict__ thr) {
    const int b = blockIdx.x;
    if (fb[b]) return;
    __shared__ unsigned hist[256];
    __shared__ unsigned sj, spre;
    const long base = (long)b * HW_N;
    if (threadIdx.x == 0) { sj = kval[b]; spre = 0u; }
    __syncthreads();
    for (int pass = 0; pass < 4; ++pass) {
        const int shift = 24 - 8 * pass;
        hist[threadIdx.x] = 0u;
        __syncthreads();
        const unsigned pref = spre;
        for (int i = threadIdx.x; i < HW_N; i += 256) {
            if ((pk8b[base + i] >> 2) != 0u) continue;   // pos pixel
            unsigned key = f2key(Tl[base + i]);
            if (pass == 0 || (key >> (shift + 8)) == pref)
                atomicAdd(&hist[(key >> shift) & 0xFFu], 1u);
        }
        __syncthreads();
        if (threadIdx.x == 0) {
            unsigned j = sj, cum = 0;
            for (int d = 255; d >= 0; --d) {
                cum += hist[d];
                if (cum >= j) {
                    sj = j - (cum - hist[d]);
                    spre = (pref << 8) | (unsigned)d;
                    break;
                }
            }
        }
        __syncthreads();
    }
    if (threadIdx.x == 0) thr[b] = key2f(spre);
}

// ---------------------------------------------------------------------------
// K_NEGFIX: rare path only — SUBTRACT pt^2 of excluded negatives (tl < thr).
// ---------------------------------------------------------------------------
__global__ __launch_bounds__(256)
void k_negfix(const float4* __restrict__ Tl, const unsigned* __restrict__ pk8,
              const unsigned* __restrict__ fb, const float* __restrict__ thr,
              float* __restrict__ k1s) {
    const int b = blockIdx.y;
    if (fb[b]) return;
    const int tid = threadIdx.x;
    const long base4 = (long)b * HW4;
    const float tb = thr[b];
    float acc = 0.f;
#pragma unroll
    for (int it = 0; it < 2; ++it) {
        const int i4 = blockIdx.x * 512 + it * 256 + tid;
        const float4 tl4 = Tl[base4 + i4];
        const unsigned pkw = pk8[base4 + i4];
#pragma unroll
        for (int p = 0; p < 4; ++p) {
            unsigned byte = (pkw >> (8 * p)) & 0xFFu;
            bool tmb = byte & 1u;
            bool neg = (byte >> 2) == 0u;
            float tl = f4c(tl4, p);
            if (neg && tmb && tl < tb) {
                float pt = 1.f / (1.f + __expf(-tl));
                acc = fmaf(pt, pt, acc);
            }
        }
    }
    acc = wred64(acc);
    __shared__ float wa[4];
    if ((tid & 63) == 0) wa[tid >> 6] = acc;
    __syncthreads();
    if (tid == 0) {
        float s = wa[0] + wa[1] + wa[2] + wa[3];
        if (s != 0.f) atomicAdd(&k1s[b * NP + J_BTN], -s);
    }
}

// ---------------------------------------------------------------------------
// K5: aggregation pass — Fv + packed plane, pinned batched loads; register
// accumulators for sum_l and cnt_t; 16 global atomics per block.
// ---------------------------------------------------------------------------
__global__ __launch_bounds__(256)
void k5_agg(const unsigned* __restrict__ pk8, const float4* __restrict__ Fv,
            const float* __restrict__ kms, float* __restrict__ slg) {
    const int b = blockIdx.y;
    const int tid = threadIdx.x, wid = tid >> 6, lane = tid & 63;
    __shared__ float Kml[32];
    __shared__ float wacc[4][16];
    if (tid < 32) Kml[tid] = kms[b * 32 + tid];
    __syncthreads();
    const long base4 = (long)b * HW4;
    const long f04 = (long)b * 4 * HW4;
    const int i0 = blockIdx.x * 512 + tid;
    const int i1 = i0 + 256;

    // ---- issue ALL 10 loads, then pin ----
    const unsigned pkwA = pk8[base4 + i0], pkwB = pk8[base4 + i1];
    const float4 f0A = Fv[f04 + i0],           f0B = Fv[f04 + i1];
    const float4 f1A = Fv[f04 + HW4 + i0],     f1B = Fv[f04 + HW4 + i1];
    const float4 f2A = Fv[f04 + 2 * HW4 + i0], f2B = Fv[f04 + 2 * HW4 + i1];
    const float4 f3A = Fv[f04 + 3 * HW4 + i0], f3B = Fv[f04 + 3 * HW4 + i1];
    asm volatile("" ::
        "v"(pkwA), "v"(pkwB),
        "v"(f0A.x), "v"(f0B.x), "v"(f1A.x), "v"(f1B.x),
        "v"(f2A.x), "v"(f2B.x), "v"(f3A.x), "v"(f3B.x));

    float sl8[8] = {0.f, 0.f, 0.f, 0.f, 0.f, 0.f, 0.f, 0.f};
    float ct8[8] = {0.f, 0.f, 0.f, 0.f, 0.f, 0.f, 0.f, 0.f};

#pragma unroll
    for (int it = 0; it < 2; ++it) {
        const unsigned pkw = it ? pkwB : pkwA;
        const float4 F0v = it ? f0B : f0A;
        const float4 F1v = it ? f1B : f1A;
        const float4 F2v = it ? f2B : f2A;
        const float4 F3v = it ? f3B : f3A;
#pragma unroll
        for (int p = 0; p < 4; ++p) {
            unsigned byte = (pkw >> (8 * p)) & 0xFFu;
            int lt = ((byte & 3u) == 3u) ? (int)(byte >> 2) : 0;
            int kb = (lt > 0 ? lt - 1 : 0) * 4;
            float d0 = f4c(F0v, p) - Kml[kb + 0];
            float d1 = f4c(F1v, p) - Kml[kb + 1];
            float d2 = f4c(F2v, p) - Kml[kb + 2];
            float d3 = f4c(F3v, p) - Kml[kb + 3];
            float d = sqrtf(fmaf(d0, d0, fmaf(d1, d1, fmaf(d2, d2, d3 * d3))));
            float t = fmaxf(d - 0.5f, 0.f);
            float pl = __logf(fmaf(t, t, 1.f));
#pragma unroll
            for (int s = 1; s <= 8; ++s) {
                float e = (lt == s) ? 1.f : 0.f;
                sl8[s - 1] = fmaf(e, pl, sl8[s - 1]);
                ct8[s - 1] += e;
            }
        }
    }

#pragma unroll
    for (int j = 0; j < 8; ++j) { sl8[j] = wred64(sl8[j]); ct8[j] = wred64(ct8[j]); }
    if (lane == 0) {
#pragma unroll
        for (int j = 0; j < 8; ++j) { wacc[wid][j] = sl8[j]; wacc[wid][8 + j] = ct8[j]; }
    }
    __syncthreads();
    if (tid < 16) {
        float v = wacc[0][tid] + wacc[1][tid] + wacc[2][tid] + wacc[3][tid];
        atomicAdd(&slg[b * 16 + tid], v);
    }
}

// ---------------------------------------------------------------------------
// K6: final combine -> scalar loss.
// ---------------------------------------------------------------------------
__global__ __launch_bounds__(512)
void k6_final(const float* __restrict__ k1s, const float* __restrict__ kms,
              const float* __restrict__ slg, float* __restrict__ out) {
    const int tid = threadIdx.x;
    const int b = tid >> 6, lane = tid & 63;
    __shared__ float KmS[BATCH * 32];
    __shared__ float laS[BATCH], ldS[BATCH];
    if (tid < BATCH * 32) KmS[tid] = kms[tid];
    __syncthreads();
    const float* s1 = k1s + b * NP;

    float aggs = 0.f, aggc = 0.f;
    if (lane >= 1 && lane <= 8) {
        float ctv = slg[b * 16 + 8 + lane - 1];
        float ckv = s1[J_CNTK + lane - 1];
        if (ctv > 0.f && ckv > 0.f) {
            aggs = slg[b * 16 + lane - 1] / fmaxf(ctv, 1.f);
            aggc = 1.f;
        }
    }
    float diss = 0.f, disc = 0.f;
    {
        int i = 1 + (lane >> 3), j = 1 + (lane & 7);
        if (i != j && s1[J_CNTK + i - 1] > 0.f && s1[J_CNTK + j - 1] > 0.f) {
            float d2 = 0.f;
#pragma unroll
            for (int c = 0; c < 4; ++c) {
                float df = KmS[b * 32 + (i - 1) * 4 + c] -
                           KmS[b * 32 + (j - 1) * 4 + c];
                d2 = fmaf(df, df, d2);
            }
            float kd = sqrtf(d2);
            float t = fmaxf(3.f - kd, 0.f);
            diss = logf(t * t + 1.f);
            disc = 1.f;
        }
    }
    aggs = wred64(aggs); aggc = wred64(aggc);
    diss = wred64(diss); disc = wred64(disc);
    if (lane == 0) {
        laS[b] = aggs / fmaxf(aggc, 1.f);
        ldS[b] = diss / fmaxf(disc, 1.f);
    }
    __syncthreads();
    if (tid == 0) {
        float Lt = 0.f, Lk = 0.f, La = 0.f, Ld = 0.f;
        for (int bb = 0; bb < BATCH; ++bb) {
            const float* a = k1s + bb * NP;
            Lk += 1.f - 2.f * a[J_AK] / ((a[J_BK] + 1e-6f) + (a[J_CK] + 1e-6f));
            float btv = a[J_BTP] + a[J_BTN];
            Lt += 1.f - 2.f * a[J_AT] / ((btv + 1e-6f) + (a[J_CPOS] + 1e-6f));
            La += laS[bb]; Ld += ldS[bb];
        }
        out[0] = Lt / BATCH + 0.5f * (Lk / BATCH) + 0.25f * (La / BATCH + Ld / BATCH);
    }
}

// ---------------------------------------------------------------------------
extern "C" void kernel_launch(void* const* d_in, const int* in_sizes, int n_in,
                              void* d_out, int out_size, void* d_ws, size_t ws_size,
                              hipStream_t stream) {
    (void)in_sizes; (void)n_in; (void)out_size; (void)ws_size;
    const float4* Tl = (const float4*)d_in[0];   // pre_text_logits
    const float4* Kl = (const float4*)d_in[1];   // pre_kernel_logits
    const float4* Fv = (const float4*)d_in[2];   // similarity_vector [B,C,H,W]
    const float4* Tm = (const float4*)d_in[5];   // train_mask
    const int4* Ltk = (const int4*)d_in[6];      // gt_text_key
    const int4* Lkk = (const int4*)d_in[7];      // gt_kernel_key
    float* out = (float*)d_out;

    // ws layout (4B units). memset region first: k1s, slg, minkeyinv.
    float* k1s = (float*)d_ws;                           // 8*48 = 384
    float* slg = k1s + BATCH * NP;                       // 8*16 = 128
    unsigned* minkeyinv = (unsigned*)(slg + BATCH * 16); // 8
    float* thr = (float*)(minkeyinv + BATCH);            // 8
    unsigned* kval = (unsigned*)(thr + BATCH);           // 8
    unsigned* fb = kval + BATCH;                         // 8
    float* kms = (float*)(fb + BATCH);                   // 8*32 = 256
    float* part = kms + BATCH * 32;                      // 8*48*200 = 76800
    unsigned* pk8 = (unsigned*)(part + (size_t)BATCH * NP * NBLK); // 8*HW4

    hipMemsetAsync(d_ws, 0, (size_t)(BATCH * NP + BATCH * 16 + BATCH) * 4, stream);

    dim3 g(NBLK, BATCH);
    k1_main<<<g, 256, 0, stream>>>(Tl, Kl, Fv, Tm, Ltk, Lkk, part, pk8, minkeyinv);
    k1_reduce<<<BATCH, 256, 0, stream>>>(part, minkeyinv, k1s, kms, thr, kval, fb);
    k_rare<<<BATCH, 256, 0, stream>>>((const float*)d_in[0],
                                      (const unsigned char*)pk8, fb, kval, thr);
    k_negfix<<<g, 256, 0, stream>>>(Tl, pk8, fb, thr, k1s);
    k5_agg<<<g, 256, 0, stream>>>(pk8, Fv, kms, slg);
    k6_final<<<1, 512, 0, stream>>>(k1s, kms, slg, out);
}